// Round 9
// baseline (719.298 us; speedup 1.0000x reference)
//
#include <hip/hip_runtime.h>

#define EMBD 300
#define NSTEP 300
#define HID 512
#define G4 2048
#define TPB 256
#define NWG 32

#define TS2 15              // steps per phase-1 step-group
#define NSG 20              // step groups (20*15 = 300)
#define NRG 8               // row groups (8*256 = 2048 rows)

#define SENTINEL 0xFFC00000u   // quiet NaN: h values are always finite

// ws float layout:
//   [0 .. 614400)      : X_proj [300][2048]
//   [614400 .. +154112): HSEQ [301][512]  (h state before each step)
#define XP_SZ    (NSTEP * G4)
#define HSEQ_OFF XP_SZ

__device__ __forceinline__ float fsig(float x) { return 1.0f / (1.0f + __expf(-x)); }
__device__ __forceinline__ float ftanh(float x) {
    x = fminf(15.0f, fmaxf(-15.0f, x));
    float t = __expf(2.0f * x);
    return (t - 1.0f) / (t + 1.0f);
}

// Phase 1: X_proj[t][r] = b_ih[r]+b_hh[r] + sum_e W_ih[r][e]*emb[x[t]][e]
// Grid (NRG, NSG). rowg==0 blocks sentinel-clear HSEQ rows t0+1..t0+15;
// (0,0) also copies h0 into HSEQ[0]. Re-done every call -> replay-safe.
__global__ __launch_bounds__(TPB) void xproj_init_kernel(
    const int* __restrict__ x, const float* __restrict__ h0,
    const float* __restrict__ emb, const float* __restrict__ W_ih,
    const float* __restrict__ b_ih, const float* __restrict__ b_hh,
    float* __restrict__ ws) {
    const int rowg = blockIdx.x;      // 0..7
    const int sg   = blockIdx.y;      // 0..19
    const int tid  = threadIdx.x;
    const int t0   = sg * TS2;
    const int r    = rowg * TPB + tid;

    float* hseq = ws + HSEQ_OFF;

    if (rowg == 0) {
        unsigned* hs = (unsigned*)(hseq + (size_t)(t0 + 1) * HID);
        for (int i = tid; i < TS2 * HID; i += TPB) hs[i] = SENTINEL;
        if (sg == 0) {
            for (int i = tid; i < HID; i += TPB) hseq[i] = h0[i];
        }
    }

    __shared__ float e_lds[TS2][EMBD];
    for (int tt = 0; tt < TS2; ++tt) {
        const float* er = emb + (long long)x[t0 + tt] * EMBD;
        for (int i = tid; i < EMBD; i += TPB) e_lds[tt][i] = er[i];
    }
    __syncthreads();

    float acc[TS2];
    const float bsum = b_ih[r] + b_hh[r];
    #pragma unroll
    for (int tt = 0; tt < TS2; ++tt) acc[tt] = bsum;

    const float* wrow = W_ih + (size_t)r * EMBD;
    for (int e = 0; e < EMBD; e += 4) {
        const float4 w4 = *(const float4*)(wrow + e);
        #pragma unroll
        for (int tt = 0; tt < TS2; ++tt) {
            acc[tt] = fmaf(w4.x, e_lds[tt][e],     acc[tt]);
            acc[tt] = fmaf(w4.y, e_lds[tt][e + 1], acc[tt]);
            acc[tt] = fmaf(w4.z, e_lds[tt][e + 2], acc[tt]);
            acc[tt] = fmaf(w4.w, e_lds[tt][e + 3], acc[tt]);
        }
    }
    #pragma unroll
    for (int tt = 0; tt < TS2; ++tt)
        ws[(size_t)(t0 + tt) * G4 + r] = acc[tt];
}

// Phase 2: R1 structure (measured best) with ONE barrier per step.
// 32 WGs x 256 threads. 16-lane group (v,g) owns hidx = wg*16+v*4+g, all 4
// gates; lane li covers cols [li*32, li*32+32). Every thread polls its own
// 8B slot of HSEQ[s] (relaxed agent atomics + s_sleep backoff, R1-proven),
// fills DOUBLE-BUFFERED LDS; single __syncthreads (fill->compute). The
// end-of-step barrier is dropped: fill@s+2 into buf[s&1] is ordered after
// all same-WG reads@s via reads -> (shuffle dep) -> own publish@s+1 ->
// foreign detect@s+1 -> foreign publish@s+2 -> own detect@s+2 -> fill.
// Distance-1 reuse uses the other buffer.
__global__ __launch_bounds__(TPB, 1) void lstm_scan_kernel(
    const float* __restrict__ c0, const float* __restrict__ W_hh,
    const float* __restrict__ fc_w, const float* __restrict__ fc_b,
    float* __restrict__ ws, float* __restrict__ out) {
    const int tid  = threadIdx.x;
    const int wg   = blockIdx.x;
    const int v    = tid >> 6;     // wave id
    const int lane = tid & 63;
    const int g    = lane >> 4;    // group within wave
    const int li   = lane & 15;    // lane within group (column split)
    const int hidx = wg * 16 + v * 4 + g;

    float* hseq     = ws + HSEQ_OFF;        // [301][512]
    const float* xp = ws;                   // [300][2048]

    __shared__ __align__(16) float h_lds[2][576];  // idx i -> i + 4*(i>>5)
    __shared__ float red[256];

    // wreg[gate][k] = W_hh[(gate*HID + hidx)*HID + li*32 + k]
    float wreg[4][32];
    #pragma unroll
    for (int gate = 0; gate < 4; ++gate) {
        const float* wr = W_hh + ((size_t)gate * HID + hidx) * HID + li * 32;
        #pragma unroll
        for (int k = 0; k < 32; k += 4) {
            const float4 w4 = *(const float4*)(wr + k);
            wreg[gate][k] = w4.x; wreg[gate][k + 1] = w4.y;
            wreg[gate][k + 2] = w4.z; wreg[gate][k + 3] = w4.w;
        }
    }

    const bool upd = (li == 0);
    float c = upd ? c0[hidx] : 0.0f;

    for (int s = 0; s < NSTEP; ++s) {
        // X_proj loads issued before the poll -> latency hidden under it.
        float xi = 0.f, xf = 0.f, xg = 0.f, xo = 0.f;
        if (upd) {
            const float* xpt = xp + (size_t)s * G4 + hidx;
            xi = xpt[0]; xf = xpt[HID]; xg = xpt[2 * HID]; xo = xpt[3 * HID];
        }

        // Poll own 8B slot of HSEQ[s] (both 4B halves flip independently).
        {
            const unsigned long long* slot =
                (const unsigned long long*)(hseq + (size_t)s * HID) + tid;
            unsigned long long hv = __hip_atomic_load(slot, __ATOMIC_RELAXED,
                                                      __HIP_MEMORY_SCOPE_AGENT);
            while ((unsigned)hv == SENTINEL || (unsigned)(hv >> 32) == SENTINEL) {
                __builtin_amdgcn_s_sleep(1);
                hv = __hip_atomic_load(slot, __ATOMIC_RELAXED,
                                       __HIP_MEMORY_SCOPE_AGENT);
            }
            const int i0 = 2 * tid;
            *(float2*)&h_lds[s & 1][i0 + ((i0 >> 5) << 2)] =
                make_float2(__uint_as_float((unsigned)hv),
                            __uint_as_float((unsigned)(hv >> 32)));
        }
        __syncthreads();   // fill -> compute (the ONLY barrier per step)

        // 4 gate rows for hidx: 32 cols/lane + 4-stage butterfly (16-lane).
        float sums[4];
        const float* hrow = &h_lds[s & 1][li * 36];
        #pragma unroll
        for (int gate = 0; gate < 4; ++gate) {
            float acc = 0.0f;
            #pragma unroll
            for (int k = 0; k < 32; k += 4) {
                const float4 h4 = *(const float4*)(hrow + k);
                acc = fmaf(wreg[gate][k],     h4.x, acc);
                acc = fmaf(wreg[gate][k + 1], h4.y, acc);
                acc = fmaf(wreg[gate][k + 2], h4.z, acc);
                acc = fmaf(wreg[gate][k + 3], h4.w, acc);
            }
            acc += __shfl_xor(acc, 1);
            acc += __shfl_xor(acc, 2);
            acc += __shfl_xor(acc, 4);
            acc += __shfl_xor(acc, 8);
            sums[gate] = acc;
        }

        if (upd) {
            const float iv = fsig(sums[0] + xi);
            const float fv = fsig(sums[1] + xf);
            const float gv = ftanh(sums[2] + xg);
            const float ov = fsig(sums[3] + xo);
            c = fv * c + iv * gv;
            const float h = ov * ftanh(c);
            __hip_atomic_store((unsigned*)(hseq + (size_t)(s + 1) * HID + hidx),
                               __float_as_uint(h),
                               __ATOMIC_RELAXED, __HIP_MEMORY_SCOPE_AGENT);
            if (s == NSTEP - 1) {
                out[1 + hidx] = h;
                out[1 + HID + hidx] = c;
            }
        }
    }

    // Epilogue: WG 0 computes out[0] = sigmoid(fc_w . h_300 + fc_b).
    if (wg == 0) {
        const unsigned long long* slot =
            (const unsigned long long*)(hseq + (size_t)NSTEP * HID) + tid;
        unsigned long long hv = __hip_atomic_load(slot, __ATOMIC_RELAXED,
                                                  __HIP_MEMORY_SCOPE_AGENT);
        while ((unsigned)hv == SENTINEL || (unsigned)(hv >> 32) == SENTINEL) {
            __builtin_amdgcn_s_sleep(1);
            hv = __hip_atomic_load(slot, __ATOMIC_RELAXED,
                                   __HIP_MEMORY_SCOPE_AGENT);
        }
        red[tid] = __uint_as_float((unsigned)hv) * fc_w[2 * tid]
                 + __uint_as_float((unsigned)(hv >> 32)) * fc_w[2 * tid + 1];
        __syncthreads();
        for (int off = 128; off > 0; off >>= 1) {
            if (tid < off) red[tid] += red[tid + off];
            __syncthreads();
        }
        if (tid == 0) out[0] = fsig(red[0] + fc_b[0]);
    }
}

extern "C" void kernel_launch(void* const* d_in, const int* in_sizes, int n_in,
                              void* d_out, int out_size, void* d_ws, size_t ws_size,
                              hipStream_t stream) {
    (void)in_sizes; (void)n_in; (void)out_size; (void)ws_size;
    const int*   x     = (const int*)d_in[0];
    const float* h0    = (const float*)d_in[1];
    const float* c0    = (const float*)d_in[2];
    const float* emb   = (const float*)d_in[3];
    const float* W_ih  = (const float*)d_in[4];
    const float* W_hh  = (const float*)d_in[5];
    const float* b_ih  = (const float*)d_in[6];
    const float* b_hh  = (const float*)d_in[7];
    const float* fc_w  = (const float*)d_in[8];
    const float* fc_b  = (const float*)d_in[9];
    float* out = (float*)d_out;
    float* ws  = (float*)d_ws;

    xproj_init_kernel<<<dim3(NRG, NSG), dim3(TPB), 0, stream>>>(
        x, h0, emb, W_ih, b_ih, b_hh, ws);
    lstm_scan_kernel<<<dim3(NWG), dim3(TPB), 0, stream>>>(
        c0, W_hh, fc_w, fc_b, ws, out);
}